// Round 6
// baseline (149.140 us; speedup 1.0000x reference)
//
#include <hip/hip_runtime.h>
#include <hip/hip_bf16.h>
#include <stdint.h>

#define AS1 __attribute__((address_space(1)))
#define AS3 __attribute__((address_space(3)))

typedef float  f32x4  __attribute__((ext_vector_type(4)));
typedef __bf16 bf16x8 __attribute__((ext_vector_type(8)));
typedef __bf16 bf16x2 __attribute__((ext_vector_type(2)));
typedef short  s16x8  __attribute__((ext_vector_type(8)));

static constexpr int Bc = 16, Sc = 512, Hc = 768, NSPAN = 4068;
static constexpr int BM = 128, BN = 256, BK = 64, KS = Hc / BK; // 12 k-steps

static __device__ __forceinline__ uint32_t pack2bf(float x, float y) {
  bf16x2 p;
  p[0] = (__bf16)x;
  p[1] = (__bf16)y;
  return __builtin_bit_cast(uint32_t, p);
}

// ---------------- prep: W1^T -> bf16, chunk-swizzled (16B chunks XORed by n&7 within 128B k-groups) ----------------
__global__ __launch_bounds__(256)
void prep_w1t(const float* __restrict__ w_lin, unsigned short* __restrict__ w1t) {
  __shared__ __align__(16) unsigned short T[64][80];
  int bidk = blockIdx.x % 12, bidn = blockIdx.x / 12;
  int k0 = bidk * 64, n0 = bidn * 64;
  int tid = threadIdx.x;
#pragma unroll
  for (int p = 0; p < 16; ++p) {
    int idx = p * 256 + tid;
    int kl = idx >> 6, nl = idx & 63;
    float v = w_lin[(size_t)(k0 + kl) * Hc + (n0 + nl)];
    __bf16 bv = (__bf16)v;
    T[nl][kl] = __builtin_bit_cast(unsigned short, bv);
  }
  __syncthreads();
#pragma unroll
  for (int qq = 0; qq < 2; ++qq) {
    int q = qq * 256 + tid;
    int nl = q >> 3, c = q & 7;
    int n = n0 + nl;
    int gp = (k0 >> 3) + (c ^ (n & 7));
    s16x8 v = *(const s16x8*)(&T[nl][c * 8]);
    *(s16x8*)(w1t + (size_t)n * Hc + gp * 8) = v;
  }
}

// ---------------- cls projection (fp32 exact, bias folded) + token_inputs copy ----------------
__global__ __launch_bounds__(256)
void cls_proj_kernel(const float* __restrict__ emb, const float* __restrict__ w_lin,
                     const float* __restrict__ b_lin, float* __restrict__ out,
                     float* __restrict__ cls_proj) {
  __shared__ float cls_s[Hc];
  int b = blockIdx.x / 3, hc = blockIdx.x % 3;
  int tid = threadIdx.x;
  const float* cls = emb + (size_t)b * Sc * Hc;
  for (int i = tid; i < Hc; i += 256) cls_s[i] = cls[i];
  __syncthreads();
  int h = hc * 256 + tid;
  const float* wp = w_lin + (size_t)Hc * Hc + h;
  float p0 = 0, p1 = 0, p2 = 0, p3 = 0, p4 = 0, p5 = 0, p6 = 0, p7 = 0;
  for (int f = 0; f < Hc; f += 8) {
    p0 += cls_s[f + 0] * wp[(size_t)(f + 0) * Hc];
    p1 += cls_s[f + 1] * wp[(size_t)(f + 1) * Hc];
    p2 += cls_s[f + 2] * wp[(size_t)(f + 2) * Hc];
    p3 += cls_s[f + 3] * wp[(size_t)(f + 3) * Hc];
    p4 += cls_s[f + 4] * wp[(size_t)(f + 4) * Hc];
    p5 += cls_s[f + 5] * wp[(size_t)(f + 5) * Hc];
    p6 += cls_s[f + 6] * wp[(size_t)(f + 6) * Hc];
    p7 += cls_s[f + 7] * wp[(size_t)(f + 7) * Hc];
  }
  float acc = b_lin[h] + (((p0 + p1) + (p2 + p3)) + ((p4 + p5) + (p6 + p7)));
  cls_proj[b * Hc + h] = acc;
  out[b * Hc + h] = cls_s[h];
}

// ---------------- fused span-max + GEMM + epilogue: 8-wave 128x256 phase-split pipeline ----------------
__global__ __launch_bounds__(512, 2)
void span_gemm(const float* __restrict__ emb, const unsigned short* __restrict__ w1t,
               const float* __restrict__ cls_proj, const float* __restrict__ w_lin,
               float* __restrict__ out) {
  __shared__ __align__(16) unsigned short Ald[2][BM * BK]; // 2 x 16 KB, swizzled [m][64] bf16
  __shared__ __align__(16) unsigned short Bld[2][BN * BK]; // 2 x 32 KB, swizzled [n][64] bf16

  // bijective XCD-chunked swizzle: 1536 = 8 x 192
  int wg = blockIdx.x;
  int wgid = (wg & 7) * 192 + (wg >> 3);
  int tile_n = wgid % 3, tile_m = wgid / 3;   // 512 m-tiles x 3 n-tiles
  int b = tile_m >> 5;                        // 32 m-tiles per batch
  int s0 = (tile_m & 31) << 4;                // 16 starts per tile
  int n0 = tile_n << 8;
  int tid = threadIdx.x;
  int wid = tid >> 6, lane = tid & 63;
  int wave_m = wid >> 2, wave_n = wid & 3;    // 2 x 4 waves, 64x64 each
  int lq = lane >> 4, lr = lane & 15;

  const char* embC = (const char*)(emb + (size_t)b * Sc * Hc);

  // A-build item: start i = tid>>5 (0..15), k-pair kp = tid&31 (float2 at k=2*kp... kp*2 floats)
  int bi = tid >> 5, kp = tid & 31;
  uint32_t rowoff[8];
#pragma unroll
  for (int t = 0; t < 8; ++t) {
    int r = s0 + bi + t;
    if (r > 511) r = 511; // clamped rows feed only discarded outputs
    rowoff[t] = (uint32_t)r * (Hc * 4) + kp * 8;
  }
  int awbase = (bi << 10) + ((kp & 3) << 2);

  f32x4 acc[4][4];
  f32x4 zer = {0.f, 0.f, 0.f, 0.f};
#pragma unroll
  for (int i = 0; i < 4; ++i)
#pragma unroll
    for (int j = 0; j < 4; ++j) acc[i][j] = zer;

  float2 rv[8];

#define LOAD_RV(koff)                                                          \
  _Pragma("unroll") for (int t = 0; t < 8; ++t)                                \
      rv[t] = *(const float2*)(embC + rowoff[t] + (koff));

#define BUILD_A(dstbuf)                                                        \
  {                                                                            \
    float2 cm = rv[0];                                                         \
    _Pragma("unroll") for (int t = 0; t < 8; ++t) {                            \
      if (t) {                                                                 \
        cm.x = fmaxf(cm.x, rv[t].x);                                           \
        cm.y = fmaxf(cm.y, rv[t].y);                                           \
      }                                                                        \
      int off = awbase + (t << 7) + (((kp >> 2) ^ t) << 4);                    \
      *(uint32_t*)((char*)(dstbuf) + off) = pack2bf(cm.x, cm.y);               \
    }                                                                          \
  }

#define GLL_B(k0, dstbuf)                                                      \
  _Pragma("unroll") for (int j = 0; j < 4; ++j) {                              \
    int u = (wid << 2) + j;                                                    \
    int n = n0 + (u << 3) + (lane >> 3);                                       \
    const unsigned short* gp = w1t + (size_t)n * Hc + (k0) + ((lane & 7) << 3);\
    __builtin_amdgcn_global_load_lds((const AS1 uint32_t*)gp,                  \
                                     (AS3 uint32_t*)((dstbuf) + (u << 9)), 16, 0, 0); \
  }

#define READ_FRAGS(buf, kk, af, bfr)                                           \
  {                                                                            \
    int cf = ((kk) << 2) + lq;                                                 \
    _Pragma("unroll") for (int mi = 0; mi < 4; ++mi) {                         \
      int m = (wave_m << 6) + (mi << 4) + lr;                                  \
      af[mi] = *(const bf16x8*)((const char*)Ald[buf] + (m << 7) + ((cf ^ (m & 7)) << 4)); \
    }                                                                          \
    _Pragma("unroll") for (int ni = 0; ni < 4; ++ni) {                         \
      int n = (wave_n << 6) + (ni << 4) + lr;                                  \
      bfr[ni] = *(const bf16x8*)((const char*)Bld[buf] + (n << 7) + ((cf ^ (n & 7)) << 4)); \
    }                                                                          \
  }

#define MFMA16(af, bfr)                                                        \
  __builtin_amdgcn_s_setprio(1);                                               \
  _Pragma("unroll") for (int mi = 0; mi < 4; ++mi)                             \
    _Pragma("unroll") for (int ni = 0; ni < 4; ++ni)                           \
      acc[mi][ni] = __builtin_amdgcn_mfma_f32_16x16x32_bf16(af[mi], bfr[ni], acc[mi][ni], 0, 0, 0); \
  __builtin_amdgcn_s_setprio(0);

  // ---- prologue: build A[0]; issue B[0]; prefetch rv = emb[1] ----
  LOAD_RV(0);
  BUILD_A(Ald[0]);        // waits rv (only outstanding loads)
  GLL_B(0, Bld[0]);       // 4 gll in flight
  LOAD_RV(256);           // 8 rv newer than gll
  asm volatile("s_waitcnt vmcnt(8) lgkmcnt(0)" ::: "memory"); // drain gll; keep rv
  __builtin_amdgcn_sched_barrier(0);
  __builtin_amdgcn_s_barrier();
  __builtin_amdgcn_sched_barrier(0);

  for (int ks = 0; ks < KS - 1; ++ks) {
    int cur = ks & 1, nb = cur ^ 1;
    // P1: ds_read kk0 -> MFMA
    {
      bf16x8 af[4], bfr[4];
      READ_FRAGS(cur, 0, af, bfr);
      MFMA16(af, bfr);
    }
    // P2: issue next B (gets a phase of flight); ds_read kk1 -> MFMA
    GLL_B((ks + 1) * BK, Bld[nb]);
    {
      bf16x8 af[4], bfr[4];
      READ_FRAGS(cur, 1, af, bfr);
      MFMA16(af, bfr);
    }
    // P3: build A[ks+1] from rv (issued a full iter ago); then refill rv
    BUILD_A(Ald[nb]);
    if (ks + 2 < KS) {
      LOAD_RV((ks + 2) * 256);
      asm volatile("s_waitcnt vmcnt(8) lgkmcnt(0)" ::: "memory"); // drain gll; keep rv
    } else {
      asm volatile("s_waitcnt vmcnt(0) lgkmcnt(0)" ::: "memory");
    }
    __builtin_amdgcn_sched_barrier(0);
    __builtin_amdgcn_s_barrier();
    __builtin_amdgcn_sched_barrier(0);
  }

  // ---- final K-step: compute only ----
  {
    bf16x8 af[4], bfr[4];
    READ_FRAGS((KS - 1) & 1, 0, af, bfr);
    MFMA16(af, bfr);
  }
  {
    bf16x8 af[4], bfr[4];
    READ_FRAGS((KS - 1) & 1, 1, af, bfr);
    MFMA16(af, bfr);
  }

  // ---- epilogue: add cls_proj + width*w_last, map padded rows -> span index, store ----
  const float* w2p = w_lin + (size_t)(2 * Hc) * Hc;
  float* outp = out + Bc * Hc;
  int swb = (tile_m & 31) << 7;
  float cp[4], w2[4];
#pragma unroll
  for (int ni = 0; ni < 4; ++ni) {
    int h = n0 + (wave_n << 6) + (ni << 4) + lr;
    cp[ni] = cls_proj[b * Hc + h];
    w2[ni] = w2p[h];
  }
  int hbase = n0 + (wave_n << 6) + lr;
#pragma unroll
  for (int mi = 0; mi < 4; ++mi) {
#pragma unroll
    for (int j = 0; j < 4; ++j) {
      int m = (wave_m << 6) + (mi << 4) + (lq << 2) + j;
      int sw = swb + m;
      int s = sw >> 3, w = (sw & 7) + 1;
      if (s + w <= 512) {
        int nsp = (s <= 504) ? sw
                             : (NSPAN - (((512 - s) * (513 - s)) >> 1) + w - 1);
        float* rowp = outp + ((size_t)b * NSPAN + nsp) * Hc + hbase;
        float wf = (float)w;
#pragma unroll
        for (int ni = 0; ni < 4; ++ni)
          rowp[ni << 4] = acc[mi][ni][j] + cp[ni] + wf * w2[ni];
      }
    }
  }
}

extern "C" void kernel_launch(void* const* d_in, const int* in_sizes, int n_in,
                              void* d_out, int out_size, void* d_ws, size_t ws_size,
                              hipStream_t stream) {
  const float* emb = (const float*)d_in[0];
  const float* w_lin = (const float*)d_in[1];
  const float* b_lin = (const float*)d_in[2];
  unsigned short* w1t = (unsigned short*)d_ws;
  float* cls_proj = (float*)((char*)d_ws + (size_t)Hc * Hc * 2);
  float* out = (float*)d_out;

  hipLaunchKernelGGL(prep_w1t, dim3(144), dim3(256), 0, stream, w_lin, w1t);
  hipLaunchKernelGGL(cls_proj_kernel, dim3(48), dim3(256), 0, stream, emb, w_lin, b_lin, out, cls_proj);
  hipLaunchKernelGGL(span_gemm, dim3(1536), dim3(512), 0, stream, emb, w1t, cls_proj, w_lin, out);
}

// Round 7
// 136.580 us; speedup vs baseline: 1.0920x; 1.0920x over previous
//
#include <hip/hip_runtime.h>
#include <hip/hip_bf16.h>
#include <stdint.h>

typedef float  f32x4  __attribute__((ext_vector_type(4)));
typedef __bf16 bf16x8 __attribute__((ext_vector_type(8)));
typedef __bf16 bf16x4 __attribute__((ext_vector_type(4)));
typedef short  s16x8  __attribute__((ext_vector_type(8)));

static constexpr int Bc = 16, Sc = 512, Hc = 768, NSPAN = 4068;
static constexpr int BM = 256, BN = 256, BK = 64, KS = Hc / BK; // 12 k-tiles

// ---------------- prep: W1^T -> bf16, LINEAR [n][k] (B is consumed global->reg) ----------------
__global__ __launch_bounds__(256)
void prep_w1t(const float* __restrict__ w_lin, unsigned short* __restrict__ w1t) {
  __shared__ __align__(16) unsigned short T[64][80];
  int bidk = blockIdx.x % 12, bidn = blockIdx.x / 12;
  int k0 = bidk * 64, n0 = bidn * 64;
  int tid = threadIdx.x;
#pragma unroll
  for (int p = 0; p < 16; ++p) {
    int idx = p * 256 + tid;
    int kl = idx >> 6, nl = idx & 63;
    float v = w_lin[(size_t)(k0 + kl) * Hc + (n0 + nl)];
    __bf16 bv = (__bf16)v;
    T[nl][kl] = __builtin_bit_cast(unsigned short, bv);
  }
  __syncthreads();
#pragma unroll
  for (int qq = 0; qq < 2; ++qq) {
    int q = qq * 256 + tid;
    int nl = q >> 3, c = q & 7;
    int n = n0 + nl;
    s16x8 v = *(const s16x8*)(&T[nl][c * 8]);
    *(s16x8*)(w1t + (size_t)n * Hc + k0 + c * 8) = v;
  }
}

// ---------------- cls projection (fp32 exact, bias folded) + token_inputs copy ----------------
__global__ __launch_bounds__(256)
void cls_proj_kernel(const float* __restrict__ emb, const float* __restrict__ w_lin,
                     const float* __restrict__ b_lin, float* __restrict__ out,
                     float* __restrict__ cls_proj) {
  __shared__ float cls_s[Hc];
  int b = blockIdx.x / 3, hc = blockIdx.x % 3;
  int tid = threadIdx.x;
  const float* cls = emb + (size_t)b * Sc * Hc;
  for (int i = tid; i < Hc; i += 256) cls_s[i] = cls[i];
  __syncthreads();
  int h = hc * 256 + tid;
  const float* wp = w_lin + (size_t)Hc * Hc + h;
  float p0 = 0, p1 = 0, p2 = 0, p3 = 0, p4 = 0, p5 = 0, p6 = 0, p7 = 0;
  for (int f = 0; f < Hc; f += 8) {
    p0 += cls_s[f + 0] * wp[(size_t)(f + 0) * Hc];
    p1 += cls_s[f + 1] * wp[(size_t)(f + 1) * Hc];
    p2 += cls_s[f + 2] * wp[(size_t)(f + 2) * Hc];
    p3 += cls_s[f + 3] * wp[(size_t)(f + 3) * Hc];
    p4 += cls_s[f + 4] * wp[(size_t)(f + 4) * Hc];
    p5 += cls_s[f + 5] * wp[(size_t)(f + 5) * Hc];
    p6 += cls_s[f + 6] * wp[(size_t)(f + 6) * Hc];
    p7 += cls_s[f + 7] * wp[(size_t)(f + 7) * Hc];
  }
  float acc = b_lin[h] + (((p0 + p1) + (p2 + p3)) + ((p4 + p5) + (p6 + p7)));
  cls_proj[b * Hc + h] = acc;
  out[b * Hc + h] = cls_s[h];
}

// ---------------- fused span-max + GEMM + epilogue: 256x256 tile, A-only LDS, B in regs ----------------
// 512 threads / 8 waves (2 wave_m x 4 wave_n), each wave 128 rows x 64 cols (acc 8x4 f32x4).
__global__ __launch_bounds__(512, 2)
void span_gemm(const float* __restrict__ emb, const unsigned short* __restrict__ w1t,
               const float* __restrict__ cls_proj, const float* __restrict__ w_lin,
               float* __restrict__ out) {
  __shared__ __align__(16) unsigned short Ald[2][BM * BK]; // 2 x 32 KB, swizzled [m][64] bf16

  // bijective XCD-chunked swizzle: 768 = 8 x 96
  int wg = blockIdx.x;
  int wgid = (wg & 7) * 96 + (wg >> 3);
  int tile_n = wgid % 3, tile_m = wgid / 3;   // 256 m-tiles x 3 n-tiles
  int b = tile_m >> 4;                        // 16 m-tiles per batch (4096/256)
  int s0 = (tile_m & 15) << 5;                // 32 starts per tile
  int n0 = tile_n << 8;
  int tid = threadIdx.x;
  int wid = tid >> 6, lane = tid & 63;
  int wave_m = wid >> 2, wave_n = wid & 3;    // 2 x 4 waves, 128x64 each
  int lq = lane >> 4, lr = lane & 15;

  const char* embC = (const char*)(emb + (size_t)b * Sc * Hc);

  // A-build item: 1/thread. start i = tid>>4 (0..31), k-quad = tid&15.
  int bi = tid >> 4, bkq = tid & 15;
  uint32_t rowoff[8];
#pragma unroll
  for (int t = 0; t < 8; ++t) {
    int r = s0 + bi + t;
    if (r > 511) r = 511; // clamped rows feed only discarded outputs
    rowoff[t] = (uint32_t)r * (Hc * 4) + bkq * 16;
  }
  int awbase = (bi << 10) + ((bkq & 1) << 3);

  // B fragment base: lane lr picks n-row, lq picks 16B k-chunk (linear w1t).
  const unsigned short* bb = w1t + (size_t)(n0 + (wave_n << 6) + lr) * Hc + (lq << 3);

  f32x4 acc[8][4];
  f32x4 zer = {0.f, 0.f, 0.f, 0.f};
#pragma unroll
  for (int i = 0; i < 8; ++i)
#pragma unroll
    for (int j = 0; j < 4; ++j) acc[i][j] = zer;

  f32x4 rv[8];
  f32x4 cm;
  bf16x8 bfrA[4], bfrB[4];

#define SCHED0 __builtin_amdgcn_sched_barrier(0)

#define LOAD_RV(koff)                                                          \
  _Pragma("unroll") for (int t = 0; t < 8; ++t)                                \
      rv[t] = *(const f32x4*)(embC + rowoff[t] + (koff));

#define LOAD_BFR(dst, koff)                                                    \
  _Pragma("unroll") for (int ni = 0; ni < 4; ++ni)                             \
      dst[ni] = *(const bf16x8*)(const void*)(bb + (size_t)ni * 16 * Hc + (koff));

#define BUILD_T(an, t)                                                         \
  {                                                                            \
    if ((t) == 0) cm = rv[0];                                                  \
    else {                                                                     \
      cm[0] = fmaxf(cm[0], rv[t][0]); cm[1] = fmaxf(cm[1], rv[t][1]);          \
      cm[2] = fmaxf(cm[2], rv[t][2]); cm[3] = fmaxf(cm[3], rv[t][3]);          \
    }                                                                          \
    bf16x4 p;                                                                  \
    p[0] = (__bf16)cm[0]; p[1] = (__bf16)cm[1];                                \
    p[2] = (__bf16)cm[2]; p[3] = (__bf16)cm[3];                                \
    int off = awbase + ((t) << 7) + (((bkq >> 1) ^ (t)) << 4);                 \
    *(uint2*)((an) + off) = __builtin_bit_cast(uint2, p);                      \
  }

#define QUAD(ab, mh, kk, bfr)                                                  \
  {                                                                            \
    bf16x8 af[4];                                                              \
    int cf = ((kk) << 2) + lq;                                                 \
    _Pragma("unroll") for (int mi = 0; mi < 4; ++mi) {                         \
      int m = (wave_m << 7) + ((((mh) << 2) + mi) << 4) + lr;                  \
      af[mi] = *(const bf16x8*)((ab) + (m << 7) + ((cf ^ (m & 7)) << 4));      \
    }                                                                          \
    __builtin_amdgcn_s_setprio(1);                                             \
    _Pragma("unroll") for (int mi = 0; mi < 4; ++mi)                           \
      _Pragma("unroll") for (int ni = 0; ni < 4; ++ni)                         \
        acc[((mh) << 2) + mi][ni] = __builtin_amdgcn_mfma_f32_16x16x32_bf16(   \
            af[mi], bfr[ni], acc[((mh) << 2) + mi][ni], 0, 0, 0);              \
    __builtin_amdgcn_s_setprio(0);                                             \
  }

  // ---- prologue: build A[0]; issue bfrA(kt0,kk0); prefetch rv = emb[1] ----
  LOAD_RV(0);
  {
    char* an0 = (char*)Ald[0];
#pragma unroll
    for (int t = 0; t < 8; ++t) BUILD_T(an0, t);
  }
  LOAD_BFR(bfrA, 0);
  LOAD_RV(256);
  asm volatile("s_waitcnt lgkmcnt(0)" ::: "memory");
  SCHED0;
  __builtin_amdgcn_s_barrier();
  SCHED0;

  for (int kt = 0; kt < KS; ++kt) {
    int cur = kt & 1, nb = cur ^ 1;
    const char* ab = (const char*)Ald[cur];
    char* an = (char*)Ald[nb];

    // q0: issue bfrB(kt,kk1); MFMA quadrant (mh0, kk0)
    LOAD_BFR(bfrB, kt * 64 + 32);
    QUAD(ab, 0, 0, bfrA);
    SCHED0;
    // q1: MFMA quadrant (mh1, kk0)
    QUAD(ab, 1, 0, bfrA);
    SCHED0;
    // q2: issue bfrA(kt+1,kk0); build A[kt+1] half 0; MFMA (mh0, kk1)
    if (kt + 1 < KS) {
      LOAD_BFR(bfrA, (kt + 1) * 64);
#pragma unroll
      for (int t = 0; t < 4; ++t) BUILD_T(an, t);
    }
    QUAD(ab, 0, 1, bfrB);
    SCHED0;
    // q3: build A[kt+1] half 1; refill rv = emb[kt+2]; MFMA (mh1, kk1)
    if (kt + 1 < KS) {
#pragma unroll
      for (int t = 4; t < 8; ++t) BUILD_T(an, t);
    }
    if (kt + 2 < KS) LOAD_RV((kt + 2) * 256);
    QUAD(ab, 1, 1, bfrB);
    if (kt + 1 < KS) {
      asm volatile("s_waitcnt lgkmcnt(0)" ::: "memory");
      SCHED0;
      __builtin_amdgcn_s_barrier();
      SCHED0;
    }
  }

  // ---- epilogue: add cls_proj + width*w_last, map padded rows -> span index, store ----
  const float* w2p = w_lin + (size_t)(2 * Hc) * Hc;
  float* outp = out + Bc * Hc;
  int swb = (tile_m & 15) << 8; // s0*8
  float cp[4], w2[4];
#pragma unroll
  for (int ni = 0; ni < 4; ++ni) {
    int h = n0 + (wave_n << 6) + (ni << 4) + lr;
    cp[ni] = cls_proj[b * Hc + h];
    w2[ni] = w2p[h];
  }
  int hbase = n0 + (wave_n << 6) + lr;
#pragma unroll
  for (int mi = 0; mi < 8; ++mi) {
#pragma unroll
    for (int j = 0; j < 4; ++j) {
      int m = (wave_m << 7) + (mi << 4) + (lq << 2) + j;
      int sw = swb + m;
      int s = sw >> 3, w = (sw & 7) + 1;
      if (s + w <= 512) {
        int nsp = (s <= 504) ? sw
                             : (NSPAN - (((512 - s) * (513 - s)) >> 1) + w - 1);
        float* rowp = outp + ((size_t)b * NSPAN + nsp) * Hc + hbase;
        float wf = (float)w;
#pragma unroll
        for (int ni = 0; ni < 4; ++ni)
          rowp[ni << 4] = acc[mi][ni][j] + cp[ni] + wf * w2[ni];
      }
    }
  }
}

extern "C" void kernel_launch(void* const* d_in, const int* in_sizes, int n_in,
                              void* d_out, int out_size, void* d_ws, size_t ws_size,
                              hipStream_t stream) {
  const float* emb = (const float*)d_in[0];
  const float* w_lin = (const float*)d_in[1];
  const float* b_lin = (const float*)d_in[2];
  unsigned short* w1t = (unsigned short*)d_ws;
  float* cls_proj = (float*)((char*)d_ws + (size_t)Hc * Hc * 2);
  float* out = (float*)d_out;

  hipLaunchKernelGGL(prep_w1t, dim3(144), dim3(256), 0, stream, w_lin, w1t);
  hipLaunchKernelGGL(cls_proj_kernel, dim3(48), dim3(256), 0, stream, emb, w_lin, b_lin, out, cls_proj);
  hipLaunchKernelGGL(span_gemm, dim3(768), dim3(512), 0, stream, emb, w1t, cls_proj, w_lin, out);
}